// Round 12
// baseline (1301.142 us; speedup 1.0000x reference)
//
#include <hip/hip_runtime.h>
#include <hip/hip_cooperative_groups.h>
#include <hip/hip_bf16.h>
#include <math.h>

namespace cg = cooperative_groups;

#define B_ 2
#define A_ 9
#define N_ 1024
#define P_ 4
#define D_ 256
#define H_ 8
#define DH_ 32
#define ROWS_ (B_*N_)   // 2048
#define KS_ 8           // K-split factor for chain (k-slice 128)
#define SLABU_ 524288   // Pp slab stride in ushorts (2*16*1024*16)
#define SLABU2_ 131072  // Pp slab stride in uint2 (4 bf16 each)

typedef __attribute__((ext_vector_type(8))) short bf16x8;
typedef __attribute__((ext_vector_type(4))) float f32x4;

__device__ __forceinline__ uint pack2_bf(float x, float y) {
    uint ux = __float_as_uint(x); ux += 0x7fffu + ((ux >> 16) & 1u);
    uint uy = __float_as_uint(y); uy += 0x7fffu + ((uy >> 16) & 1u);
    return (ux >> 16) | (uy & 0xffff0000u);
}
__device__ __forceinline__ float bflo(uint u){ return __uint_as_float(u << 16); }
__device__ __forceinline__ float bfhi(uint u){ return __uint_as_float(u & 0xffff0000u); }

// ================= cooperative chain: all 4 steps + 3 reduces in ONE kernel =================
// grid 1024 x 256, exactly 4 blocks/CU co-resident. Step 3 reads fp32 adjacency and packs the
// bf16 adjp slab (block-private: each block re-reads only its own slab). T ping-pong and Pp
// cross blocks only across __threadfence()+grid.sync() (device-scope, XCD-safe).
__global__ __launch_bounds__(256, 4)
void chain_all(const float* __restrict__ adjf, ushort* __restrict__ adjp,
               const float* __restrict__ kern,
               ushort* __restrict__ T0, ushort* __restrict__ T1,
               ushort* __restrict__ Pp)
{
    cg::grid_group grid = cg::this_grid();
    __shared__ __align__(16) ushort smem[8*640 + 16*648];
    __shared__ float soft_s[8][9];
    ushort* sm_ms = smem;
    ushort* sm_t  = smem + 8*640;

    int bid    = blockIdx.x;
    int ks     = bid & (KS_-1);
    int rowblk = (bid >> 3) & 63;
    int b      = bid >> 9;
    int n0     = rowblk * 16;
    int tid    = threadIdx.x;
    int lane   = tid & 63;
    int w      = tid >> 6;

    int mr   = tid >> 4;
    int mk2  = (tid & 15) * 2;
    int mk2s = mk2 ^ ((mr & 3) << 3);
    ushort* ablk = adjp + (size_t)((b*64 + rowblk)*8 + ks) * 18432;

    int sp  = tid >> 4;
    int sk0 = (tid & 15) * 2;

    int g   = lane >> 4;
    int c15 = lane & 15;
    int gx  = (g ^ (c15 & 3)) * 8;

    for (int step = 3; step >= 0; --step) {
        const ushort* Tin = (step & 1) ? T0 : T1;
        const ushort* tbase = Tin + ((size_t)(b*16 + sp)*1024 + (size_t)ks*128) * 16;

        // per-step softmax(relu(kernels)) — identical across blocks, ~100 VALU ops
        if (tid < 8) {
            int h = tid;
            float vals[A_];
            float m = 0.0f;
            #pragma unroll
            for (int a = 0; a < A_; a++) {
                float v = kern[h*A_*P_ + a*P_ + step];
                v = v > 0.0f ? v : 0.0f;
                vals[a] = v;
                m = fmaxf(m, v);
            }
            float s = 0.0f;
            #pragma unroll
            for (int a = 0; a < A_; a++) { vals[a] = expf(vals[a] - m); s += vals[a]; }
            float inv = 1.0f / s;
            #pragma unroll
            for (int a = 0; a < A_; a++) soft_s[h][a] = vals[a] * inv;
        }
        __syncthreads();

        f32x4 acc[4];
        #pragma unroll
        for (int j = 0; j < 4; j++) acc[j] = (f32x4){0.f, 0.f, 0.f, 0.f};

        for (int chunk = 0; chunk < 4; chunk++) {
            float lo[9], hi[9];
            if (step == 3) {
                #pragma unroll
                for (int a = 0; a < A_; a++) {
                    float2 v = *(const float2*)&adjf[(((size_t)b*A_ + a)*N_ + (n0+mr))*N_
                                                     + ks*128 + chunk*32 + mk2];
                    lo[a] = v.x; hi[a] = v.y;
                }
            } else {
                #pragma unroll
                for (int a = 0; a < A_; a++) {
                    uint av = *(const uint*)&ablk[chunk*4608 + (a*16 + mr)*32 + mk2];
                    lo[a] = bflo(av); hi[a] = bfhi(av);
                }
            }
            const ushort* tsl = tbase + (size_t)(chunk*32 + sk0) * 16;
            uint4 q0 = *(const uint4*)(tsl + 0);
            uint4 q1 = *(const uint4*)(tsl + 8);
            uint4 q2 = *(const uint4*)(tsl + 16);
            uint4 q3 = *(const uint4*)(tsl + 24);

            if (step == 3) {
                #pragma unroll
                for (int a = 0; a < A_; a++)
                    *(uint*)&ablk[chunk*4608 + (a*16 + mr)*32 + mk2] = pack2_bf(lo[a], hi[a]);
            }

            if (chunk) __syncthreads();

            #pragma unroll
            for (int h = 0; h < H_; h++) {
                float s0 = soft_s[h][0]*lo[0];
                float s1 = soft_s[h][0]*hi[0];
                #pragma unroll
                for (int a = 1; a < A_; a++) { s0 += soft_s[h][a]*lo[a]; s1 += soft_s[h][a]*hi[a]; }
                *(uint*)&sm_ms[h*640 + mr*40 + mk2s] = pack2_bf(s0, s1);
            }
            {
                uint l0[4] = {q0.x, q0.y, q0.z, q0.w};
                uint l1[4] = {q1.x, q1.y, q1.z, q1.w};
                uint h0[4] = {q2.x, q2.y, q2.z, q2.w};
                uint h1[4] = {q3.x, q3.y, q3.z, q3.w};
                #pragma unroll
                for (int ci = 0; ci < 8; ci++) {
                    uint a0 = (l0[ci>>1] >> ((ci&1)*16)) & 0xffffu;
                    uint b0 = (h0[ci>>1] >> ((ci&1)*16)) & 0xffffu;
                    int k0s = sk0 ^ ((ci & 3) << 3);
                    *(uint*)&sm_t[sp*648 + ci*40 + k0s] = a0 | (b0 << 16);
                }
                #pragma unroll
                for (int ci = 0; ci < 8; ci++) {
                    int c = ci + 8;
                    uint a0 = (l1[ci>>1] >> ((ci&1)*16)) & 0xffffu;
                    uint b0 = (h1[ci>>1] >> ((ci&1)*16)) & 0xffffu;
                    int k0s = sk0 ^ ((c & 3) << 3);
                    *(uint*)&sm_t[sp*648 + c*40 + k0s] = a0 | (b0 << 16);
                }
            }
            __syncthreads();

            {
                const ushort* mb = sm_ms + c15*40 + gx;
                const ushort* tb = sm_t  + c15*40 + gx;
                #pragma unroll
                for (int j = 0; j < 4; j++) {
                    int cg2 = w + 4*j;
                    int h  = cg2 >> 1;
                    bf16x8 af  = *(const bf16x8*)&mb[h*640];
                    bf16x8 bfr = *(const bf16x8*)&tb[cg2*648];
                    acc[j] = __builtin_amdgcn_mfma_f32_16x16x32_bf16(af, bfr, acc[j], 0, 0, 0);
                }
            }
        }

        __syncthreads();
        float* Ep = (float*)smem;
        #pragma unroll
        for (int j = 0; j < 4; j++) {
            int cg2 = w + 4*j;
            #pragma unroll
            for (int i = 0; i < 4; i++)
                Ep[cg2*256 + (g*4 + i)*16 + c15] = acc[j][i];
        }
        __syncthreads();
        {
            int p = tid >> 4, r = tid & 15;
            ushort* dst = Pp + (((size_t)(ks*B_ + b)*16 + p)*N_ + (n0 + r)) * 16;
            const float* src = &Ep[p*256 + r*16];
            uint u0 = pack2_bf(src[0],  src[1]);
            uint u1 = pack2_bf(src[2],  src[3]);
            uint u2 = pack2_bf(src[4],  src[5]);
            uint u3 = pack2_bf(src[6],  src[7]);
            uint u4 = pack2_bf(src[8],  src[9]);
            uint u5 = pack2_bf(src[10], src[11]);
            uint u6 = pack2_bf(src[12], src[13]);
            uint u7 = pack2_bf(src[14], src[15]);
            *(uint4*)&dst[0] = make_uint4(u0,u1,u2,u3);
            *(uint4*)&dst[8] = make_uint4(u4,u5,u6,u7);
        }

        if (step > 0) {
            __threadfence();
            grid.sync();
            // inline reduce: sum 8 bf16 slabs (fp32 accum) -> T ping-pong buffer
            ushort* tout = (step & 1) ? T1 : T0;
            int idx = bid * 256 + tid;
            if (idx < SLABU2_) {
                float4 s = make_float4(0.f, 0.f, 0.f, 0.f);
                #pragma unroll
                for (int sl = 0; sl < KS_; sl++) {
                    uint2 v = ((const uint2*)Pp)[(size_t)sl*SLABU2_ + idx];
                    s.x += bflo(v.x); s.y += bfhi(v.x);
                    s.z += bflo(v.y); s.w += bfhi(v.y);
                }
                uint2 wv;
                wv.x = pack2_bf(s.x, s.y);
                wv.y = pack2_bf(s.z, s.w);
                ((uint2*)tout)[idx] = wv;
            }
            __threadfence();
            grid.sync();
        }
    }
}

// ---------------- V projection (SIMT, writes bf16 panels) ----------------
#define BK 16
__global__ void gemm_v(const float* __restrict__ A, const float* __restrict__ Bm,
                       const float* __restrict__ bias, ushort* __restrict__ C)
{
    __shared__ __align__(16) float As[BK][68];
    __shared__ __align__(16) float Bs[BK][68];
    int m0 = blockIdx.x * 64;
    int n0 = blockIdx.y * 64;
    int tid = threadIdx.x;
    int tx = tid & 15, ty = tid >> 4;

    float acc[4][4];
    #pragma unroll
    for (int i = 0; i < 4; i++)
        #pragma unroll
        for (int j = 0; j < 4; j++) acc[i][j] = 0.0f;

    for (int k0 = 0; k0 < D_; k0 += BK) {
        {
            int m = tid >> 2;
            int k = (tid & 3) * 4;
            float4 v = *(const float4*)&A[(size_t)(m0+m)*D_ + k0 + k];
            As[k+0][m] = v.x; As[k+1][m] = v.y; As[k+2][m] = v.z; As[k+3][m] = v.w;
        }
        {
            int k = tid >> 4;
            int n = (tid & 15) * 4;
            int c = n0 + n; int h = c >> 5; int ee = c & 31;
            float4 v = *(const float4*)&Bm[(size_t)h*D_*DH_ + (size_t)(k0+k)*DH_ + ee];
            *(float4*)&Bs[k][n] = v;
        }
        __syncthreads();
        #pragma unroll
        for (int k = 0; k < BK; k++) {
            float4 a4 = *(const float4*)&As[k][ty*4];
            float4 b4 = *(const float4*)&Bs[k][tx*4];
            acc[0][0] += a4.x*b4.x; acc[0][1] += a4.x*b4.y; acc[0][2] += a4.x*b4.z; acc[0][3] += a4.x*b4.w;
            acc[1][0] += a4.y*b4.x; acc[1][1] += a4.y*b4.y; acc[1][2] += a4.y*b4.z; acc[1][3] += a4.y*b4.w;
            acc[2][0] += a4.z*b4.x; acc[2][1] += a4.z*b4.y; acc[2][2] += a4.z*b4.z; acc[2][3] += a4.z*b4.w;
            acc[3][0] += a4.w*b4.x; acc[3][1] += a4.w*b4.y; acc[3][2] += a4.w*b4.z; acc[3][3] += a4.w*b4.w;
        }
        __syncthreads();
    }

    #pragma unroll
    for (int i = 0; i < 4; i++) {
        int row  = m0 + ty*4 + i;
        int nloc = n0 + tx*4;
        float o[4];
        #pragma unroll
        for (int j = 0; j < 4; j++) {
            int c = nloc + j;
            int h = c >> 5, ee = c & 31, n = row & (N_-1);
            o[j] = acc[i][j] + bias[(size_t)h*N_*DH_ + (size_t)n*DH_ + ee];
        }
        int bb = row >> 10, n = row & (N_-1);
        int cg2 = nloc >> 4, cc = nloc & 15;
        uint2 wv;
        wv.x = pack2_bf(o[0], o[1]);
        wv.y = pack2_bf(o[2], o[3]);
        *(uint2*)&C[(((size_t)bb*16 + cg2)*N_ + n)*16 + cc] = wv;
    }
}

// ================= FFN tail: BM=8, grid 256, 256 threads =================

// ---- gemm_r: attn(=sum bf16 Pp slabs * 1/diag(degree)) @ W0 + x -> resid(fp32); h=LN -> hbuf ----
__global__ __launch_bounds__(256, 4)
void gemm_r(const ushort* __restrict__ Pp, const float* __restrict__ degree,
            const float* __restrict__ W0, const float* __restrict__ x,
            const float* __restrict__ gamma, const float* __restrict__ beta,
            float* __restrict__ resid, ushort* __restrict__ hbuf)
{
    __shared__ __align__(16) ushort As[16*40];
    __shared__ __align__(16) ushort Bs[256*40];
    __shared__ float lnb[8*257];
    __shared__ float2 stat[8];

    int m0 = blockIdx.x * 8;
    int b  = m0 >> 10;
    int nb = m0 & (N_-1);
    int tid = threadIdx.x;
    int lane = tid & 63;
    int w = tid >> 6;
    int g = lane >> 4, c15 = lane & 15;
    int gx = (g ^ (c15 & 3)) * 8;

    int am  = tid >> 4;
    int ak2 = (tid & 15) * 2;
    int apos = am*40 + ((((ak2>>3) ^ (am&3))) << 3) + (ak2 & 7);
    float idv = 0.f;
    if (tid < 128) {
        int n = nb + am;
        idv = 1.0f / degree[((size_t)b*N_ + n)*N_ + n];
    }

    int bn8 = (tid & 31) * 8;
    int bkq = (tid >> 5) * 4;
    int bposR = ((bkq >> 3) << 3) + (bkq & 7);

    f32x4 acc[4];
    #pragma unroll
    for (int j = 0; j < 4; j++) acc[j] = (f32x4){0.f,0.f,0.f,0.f};

    for (int ksi = 0; ksi < 8; ksi++) {
        int k0 = ksi * 32;
        uint av = 0;
        if (tid < 128) {
            int k = k0 + ak2;
            size_t base = (((size_t)(b*16 + (k>>4)))*N_ + nb + am)*16 + (k & 15);
            float s0 = 0.f, s1 = 0.f;
            #pragma unroll
            for (int sl = 0; sl < 8; sl++) {
                uint v = *(const uint*)&Pp[(size_t)sl*SLABU_ + base];
                s0 += bflo(v); s1 += bfhi(v);
            }
            av = pack2_bf(s0*idv, s1*idv);
        }
        float4 lo[4], hi[4];
        #pragma unroll
        for (int i = 0; i < 4; i++) {
            lo[i] = *(const float4*)&W0[(size_t)(k0+bkq+i)*D_ + bn8];
            hi[i] = *(const float4*)&W0[(size_t)(k0+bkq+i)*D_ + bn8 + 4];
        }
        if (ksi) __syncthreads();
        if (tid < 128) *(uint*)&As[apos] = av;
        #pragma unroll
        for (int jn = 0; jn < 8; jn++) {
            int n = bn8 + jn;
            float v0 = (jn<4)? ((const float*)&lo[0])[jn] : ((const float*)&hi[0])[jn-4];
            float v1 = (jn<4)? ((const float*)&lo[1])[jn] : ((const float*)&hi[1])[jn-4];
            float v2 = (jn<4)? ((const float*)&lo[2])[jn] : ((const float*)&hi[2])[jn-4];
            float v3 = (jn<4)? ((const float*)&lo[3])[jn] : ((const float*)&hi[3])[jn-4];
            uint2 wv; wv.x = pack2_bf(v0, v1); wv.y = pack2_bf(v2, v3);
            *(uint2*)&Bs[n*40 + (bposR ^ ((n&3)<<3))] = wv;
        }
        __syncthreads();
        const ushort* ab = As + c15*40 + gx;
        #pragma unroll
        for (int nt = 0; nt < 4; nt++) {
            int n = w*64 + nt*16 + c15;
            bf16x8 af  = *(const bf16x8*)ab;
            bf16x8 bfr = *(const bf16x8*)&Bs[n*40 + gx];
            acc[nt] = __builtin_amdgcn_mfma_f32_16x16x32_bf16(af, bfr, acc[nt], 0, 0, 0);
        }
    }
    __syncthreads();

    if (g < 2) {
        #pragma unroll
        for (int nt = 0; nt < 4; nt++) {
            int c = w*64 + nt*16 + c15;
            #pragma unroll
            for (int i = 0; i < 4; i++) {
                int r = g*4 + i;
                lnb[r*257 + c] = acc[nt][i] + x[(size_t)(m0+r)*D_ + c];
            }
        }
    }
    __syncthreads();
    if (tid < 128) {
        int rr = tid >> 4, sl = tid & 15;
        float sum = 0.f, sq = 0.f;
        #pragma unroll
        for (int j = 0; j < 16; j++) {
            float v = lnb[rr*257 + sl + 16*j];
            sum += v; sq += v*v;
        }
        #pragma unroll
        for (int m = 1; m < 16; m <<= 1) { sum += __shfl_xor(sum, m); sq += __shfl_xor(sq, m); }
        if (sl == 0) {
            float mean = sum * (1.0f/D_);
            float var  = fmaxf(sq * (1.0f/D_) - mean*mean, 0.f);
            stat[rr] = make_float2(mean, rsqrtf(var + 1e-12f));
        }
    }
    __syncthreads();
    if (tid < 128) {
        int rr = tid & 7, s2 = tid >> 3;
        float2 ms = stat[rr];
        int c0 = s2 * 16;
        uint hw[8];
        #pragma unroll
        for (int q = 0; q < 4; q++) {
            int c = c0 + q*4;
            float4 v = *(const float4*)&lnb[rr*257 + c];
            *(float4*)&resid[(size_t)(m0+rr)*D_ + c] = v;
            float4 gm = *(const float4*)&gamma[c];
            float4 bt = *(const float4*)&beta[c];
            float h0 = (v.x - ms.x)*ms.y*gm.x + bt.x;
            float h1 = (v.y - ms.x)*ms.y*gm.y + bt.y;
            float h2 = (v.z - ms.x)*ms.y*gm.z + bt.z;
            float h3 = (v.w - ms.x)*ms.y*gm.w + bt.w;
            hw[2*q]   = pack2_bf(h0, h1);
            hw[2*q+1] = pack2_bf(h2, h3);
        }
        ushort* hp = &hbuf[(size_t)(m0+rr)*D_ + c0];
        *(uint4*)&hp[0] = make_uint4(hw[0], hw[1], hw[2], hw[3]);
        *(uint4*)&hp[8] = make_uint4(hw[4], hw[5], hw[6], hw[7]);
    }
}

// ---- gemm_f1: f = LN(gelu(h@W1 + b1), gf, bf) -> bf16 global ----
__global__ __launch_bounds__(256, 2)
void gemm_f1(const ushort* __restrict__ hbuf, const float* __restrict__ W1,
             const float* __restrict__ b1, const float* __restrict__ gf,
             const float* __restrict__ bfv, ushort* __restrict__ fout)
{
    __shared__ __align__(16) ushort As[16*40];
    __shared__ __align__(16) ushort Bs[512*40];
    __shared__ float lnb[8*513];
    __shared__ float2 stat[8];

    int m0 = blockIdx.x * 8;
    int tid = threadIdx.x;
    int lane = tid & 63;
    int w = tid >> 6;
    int g = lane >> 4, c15 = lane & 15;
    int gx = (g ^ (c15 & 3)) * 8;

    int am  = tid >> 4;
    int ak2 = (tid & 15) * 2;
    int apos = am*40 + ((((ak2>>3) ^ (am&3))) << 3) + (ak2 & 7);
    int bn8 = (tid & 63) * 8;
    int bk8 = (tid >> 6) * 8;

    f32x4 acc1[8];
    #pragma unroll
    for (int j = 0; j < 8; j++) acc1[j] = (f32x4){0.f,0.f,0.f,0.f};

    for (int ksi = 0; ksi < 8; ksi++) {
        int k0 = ksi * 32;
        uint av = 0;
        if (tid < 128) av = *(const uint*)&hbuf[(size_t)(m0+am)*D_ + k0 + ak2];
        float4 q[16];
        #pragma unroll
        for (int i = 0; i < 8; i++) {
            q[2*i]   = *(const float4*)&W1[(size_t)(k0+bk8+i)*(2*D_) + bn8];
            q[2*i+1] = *(const float4*)&W1[(size_t)(k0+bk8+i)*(2*D_) + bn8 + 4];
        }
        if (ksi) __syncthreads();
        if (tid < 128) *(uint*)&As[apos] = av;
        #pragma unroll
        for (int jn = 0; jn < 8; jn++) {
            int n = bn8 + jn;
            float e0 = (jn<4)? ((const float*)&q[0])[jn]  : ((const float*)&q[1])[jn-4];
            float e1 = (jn<4)? ((const float*)&q[2])[jn]  : ((const float*)&q[3])[jn-4];
            float e2 = (jn<4)? ((const float*)&q[4])[jn]  : ((const float*)&q[5])[jn-4];
            float e3 = (jn<4)? ((const float*)&q[6])[jn]  : ((const float*)&q[7])[jn-4];
            float e4 = (jn<4)? ((const float*)&q[8])[jn]  : ((const float*)&q[9])[jn-4];
            float e5 = (jn<4)? ((const float*)&q[10])[jn] : ((const float*)&q[11])[jn-4];
            float e6 = (jn<4)? ((const float*)&q[12])[jn] : ((const float*)&q[13])[jn-4];
            float e7 = (jn<4)? ((const float*)&q[14])[jn] : ((const float*)&q[15])[jn-4];
            uint4 wv;
            wv.x = pack2_bf(e0, e1); wv.y = pack2_bf(e2, e3);
            wv.z = pack2_bf(e4, e5); wv.w = pack2_bf(e6, e7);
            *(uint4*)&Bs[n*40 + ((((bk8>>3) ^ (n&3))) << 3)] = wv;
        }
        __syncthreads();
        const ushort* ab = As + c15*40 + gx;
        #pragma unroll
        for (int nt = 0; nt < 8; nt++) {
            int n = w*128 + nt*16 + c15;
            bf16x8 af  = *(const bf16x8*)ab;
            bf16x8 bfr = *(const bf16x8*)&Bs[n*40 + gx];
            acc1[nt] = __builtin_amdgcn_mfma_f32_16x16x32_bf16(af, bfr, acc1[nt], 0, 0, 0);
        }
    }
    __syncthreads();

    if (g < 2) {
        #pragma unroll
        for (int nt = 0; nt < 8; nt++) {
            int c = w*128 + nt*16 + c15;
            float bias = b1[c];
            #pragma unroll
            for (int i = 0; i < 4; i++) {
                int r = g*4 + i;
                float v = acc1[nt][i] + bias;
                v = 0.5f * v * (1.0f + erff(v * 0.70710678118654752f));
                lnb[r*513 + c] = v;
            }
        }
    }
    __syncthreads();
    if (tid < 128) {
        int rr = tid >> 4, sl = tid & 15;
        float sum = 0.f, sq = 0.f;
        #pragma unroll
        for (int j = 0; j < 32; j++) {
            float v = lnb[rr*513 + sl + 16*j];
            sum += v; sq += v*v;
        }
        #pragma unroll
        for (int m = 1; m < 16; m <<= 1) { sum += __shfl_xor(sum, m); sq += __shfl_xor(sq, m); }
        if (sl == 0) {
            float mean = sum * (1.0f/(2*D_));
            float var  = fmaxf(sq * (1.0f/(2*D_)) - mean*mean, 0.f);
            stat[rr] = make_float2(mean, rsqrtf(var + 1e-12f));
        }
    }
    __syncthreads();
    if (tid < 128) {
        int rr = tid & 7, s2 = tid >> 3;
        float2 ms = stat[rr];
        int c0 = s2 * 32;
        #pragma unroll
        for (int q = 0; q < 8; q++) {
            int c = c0 + q*4;
            float4 v = *(const float4*)&lnb[rr*513 + c];
            float4 gm = *(const float4*)&gf[c];
            float4 bt = *(const float4*)&bfv[c];
            float h0 = (v.x - ms.x)*ms.y*gm.x + bt.x;
            float h1 = (v.y - ms.x)*ms.y*gm.y + bt.y;
            float h2 = (v.z - ms.x)*ms.y*gm.z + bt.z;
            float h3 = (v.w - ms.x)*ms.y*gm.w + bt.w;
            *(uint2*)&fout[(size_t)(m0+rr)*(2*D_) + c] = make_uint2(pack2_bf(h0,h1), pack2_bf(h2,h3));
        }
    }
}

// ---- gemm_f2: out = f@W2 + b2f + resid ----
__global__ __launch_bounds__(256, 4)
void gemm_f2(const ushort* __restrict__ fbuf, const float* __restrict__ W2,
             const float* __restrict__ b2f, const float* __restrict__ resid,
             float* __restrict__ outp)
{
    __shared__ __align__(16) ushort As[16*40];
    __shared__ __align__(16) ushort Bs[256*40];
    __shared__ float esc[8*257];

    int m0 = blockIdx.x * 8;
    int tid = threadIdx.x;
    int lane = tid & 63;
    int w = tid >> 6;
    int g = lane >> 4, c15 = lane & 15;
    int gx = (g ^ (c15 & 3)) * 8;

    int am  = tid >> 4;
    int ak2 = (tid & 15) * 2;
    int apos = am*40 + ((((ak2>>3) ^ (am&3))) << 3) + (ak2 & 7);
    int bn8 = (tid & 31) * 8;
    int bkq = (tid >> 5) * 4;
    int bposR = ((bkq >> 3) << 3) + (bkq & 7);

    f32x4 acc[4];
    #pragma unroll
    for (int j = 0; j < 4; j++) acc[j] = (f32x4){0.f,0.f,0.f,0.f};

    for (int ksi = 0; ksi < 16; ksi++) {
        int k0 = ksi * 32;
        uint av = 0;
        if (tid < 128) av = *(const uint*)&fbuf[(size_t)(m0+am)*(2*D_) + k0 + ak2];
        float4 lo[4], hi[4];
        #pragma unroll
        for (int i = 0; i < 4; i++) {
            lo[i] = *(const float4*)&W2[(size_t)(k0+bkq+i)*D_ + bn8];
            hi[i] = *(const float4*)&W2[(size_t)(k0+bkq+i)*D_ + bn8 + 4];
        }
        if (ksi) __syncthreads();
        if (tid < 128) *(uint*)&As[apos] = av;
        #pragma unroll
        for (int jn = 0; jn < 8; jn++) {
            int n = bn8 + jn;
            float v0 = (jn<4)? ((const float*)&lo[0])[jn] : ((const float*)&hi[0])[jn-4];
            float v1 = (jn<4)? ((const float*)&lo[1])[jn] : ((const float*)&hi[1])[jn-4];
            float v2 = (jn<4)? ((const float*)&lo[2])[jn] : ((const float*)&hi[2])[jn-4];
            float v3 = (jn<4)? ((const float*)&lo[3])[jn] : ((const float*)&hi[3])[jn-4];
            uint2 wv; wv.x = pack2_bf(v0, v1); wv.y = pack2_bf(v2, v3);
            *(uint2*)&Bs[n*40 + (bposR ^ ((n&3)<<3))] = wv;
        }
        __syncthreads();
        const ushort* ab = As + c15*40 + gx;
        #pragma unroll
        for (int nt = 0; nt < 4; nt++) {
            int n = w*64 + nt*16 + c15;
            bf16x8 af  = *(const bf16x8*)ab;
            bf16x8 bfr = *(const bf16x8*)&Bs[n*40 + gx];
            acc[nt] = __builtin_amdgcn_mfma_f32_16x16x32_bf16(af, bfr, acc[nt], 0, 0, 0);
        }
    }
    __syncthreads();

    if (g < 2) {
        #pragma unroll
        for (int nt = 0; nt < 4; nt++) {
            int c = w*64 + nt*16 + c15;
            #pragma unroll
            for (int i = 0; i < 4; i++)
                esc[(g*4+i)*257 + c] = acc[nt][i];
        }
    }
    __syncthreads();
    if (tid < 128) {
        int rr = tid & 7, s2 = tid >> 3;
        int c0 = s2 * 16;
        #pragma unroll
        for (int q = 0; q < 4; q++) {
            int c = c0 + q*4;
            float4 v  = *(const float4*)&esc[rr*257 + c];
            float4 bb = *(const float4*)&b2f[c];
            float4 rs = *(const float4*)&resid[(size_t)(m0+rr)*D_ + c];
            float4 o = make_float4(v.x+bb.x+rs.x, v.y+bb.y+rs.y, v.z+bb.z+rs.z, v.w+bb.w+rs.w);
            *(float4*)&outp[(size_t)(m0+rr)*D_ + c] = o;
        }
    }
}

extern "C" void kernel_launch(void* const* d_in, const int* in_sizes, int n_in,
                              void* d_out, int out_size, void* d_ws, size_t ws_size,
                              hipStream_t stream)
{
    const float* adj    = (const float*)d_in[0];
    const float* degree = (const float*)d_in[1];
    const float* x      = (const float*)d_in[2];
    const float* kern   = (const float*)d_in[3];
    const float* Wv     = (const float*)d_in[4];
    const float* Bv     = (const float*)d_in[5];
    const float* W0     = (const float*)d_in[6];
    const float* gamma2 = (const float*)d_in[7];
    const float* beta2  = (const float*)d_in[8];
    const float* W1     = (const float*)d_in[9];
    const float* b1     = (const float*)d_in[10];
    const float* gf     = (const float*)d_in[11];
    const float* bf_    = (const float*)d_in[12];
    const float* W2     = (const float*)d_in[13];
    const float* b2f    = (const float*)d_in[14];
    float* out = (float*)d_out;
    float* ws  = (float*)d_ws;

    size_t off = 0;
    float* T0    = ws + off; off += (size_t)ROWS_*D_/2;     // bf16 panels (1MB)
    float* T1    = ws + off; off += (size_t)ROWS_*D_/2;
    float* resid = ws + off; off += (size_t)ROWS_*D_;       // fp32
    float* hbufF = ws + off; off += (size_t)ROWS_*D_/2;     // bf16
    float* foutF = ws + off; off += (size_t)ROWS_*D_;       // bf16 (2D cols)
    float* PpF   = ws + off; off += (size_t)KS_*ROWS_*D_/2; // bf16 slabs (8MB)
    ushort* adjp = (ushort*)(ws + off);                      // 37.75MB bf16

    ushort* T0b = (ushort*)T0;
    ushort* T1b = (ushort*)T1;
    ushort* hb  = (ushort*)hbufF;
    ushort* fb  = (ushort*)foutF;
    ushort* Pp  = (ushort*)PpF;

    gemm_v<<<dim3(ROWS_/64, D_/64), 256, 0, stream>>>(x, Wv, Bv, T0b);

    // cooperative chain: 4 MFMA steps + 3 inline reduces, one launch
    {
        void* args[] = { (void*)&adj, (void*)&adjp, (void*)&kern,
                         (void*)&T0b, (void*)&T1b, (void*)&Pp };
        hipLaunchCooperativeKernel((const void*)chain_all, dim3(B_*64*KS_), dim3(256),
                                   args, 0, stream);
    }

    gemm_r <<<ROWS_/8, 256, 0, stream>>>(Pp, degree, W0, x, gamma2, beta2, resid, hb);
    gemm_f1<<<ROWS_/8, 256, 0, stream>>>(hb, W1, b1, gf, bf_, fb);
    gemm_f2<<<ROWS_/8, 256, 0, stream>>>(fb, W2, b2f, resid, out);
}

// Round 13
// 167.155 us; speedup vs baseline: 7.7840x; 7.7840x over previous
//
#include <hip/hip_runtime.h>
#include <hip/hip_bf16.h>
#include <math.h>

#define B_ 2
#define A_ 9
#define N_ 1024
#define P_ 4
#define D_ 256
#define H_ 8
#define DH_ 32
#define ROWS_ (B_*N_)   // 2048
#define KS_ 8           // K-split factor for chain (k-slice 128)
#define SLABU_ 524288   // Pp slab stride in ushorts (2*16*1024*16)
#define SLABU2_ 131072  // Pp slab stride in uint2 (4 bf16 each)

typedef __attribute__((ext_vector_type(8))) short bf16x8;
typedef __attribute__((ext_vector_type(4))) float f32x4;

__device__ __forceinline__ uint pack2_bf(float x, float y) {
    uint ux = __float_as_uint(x); ux += 0x7fffu + ((ux >> 16) & 1u);
    uint uy = __float_as_uint(y); uy += 0x7fffu + ((uy >> 16) & 1u);
    return (ux >> 16) | (uy & 0xffff0000u);
}
__device__ __forceinline__ float bflo(uint u){ return __uint_as_float(u << 16); }
__device__ __forceinline__ float bfhi(uint u){ return __uint_as_float(u & 0xffff0000u); }

// ---------------- MFMA chain step. PACK=1: read fp32 adjacency + write bf16 adjp slab ----------------
// soft = softmax(relu(kernels)) computed IN-BLOCK (identical across blocks; no prep kernel).
// Pp partial slabs are bf16 (halves slab traffic; sum done in fp32 at the consumer).
template<int PACK>
__global__ __launch_bounds__(256, 4)
void chain_mfma(const float* __restrict__ adjf, ushort* __restrict__ adjp,
                const float* __restrict__ kern,
                const ushort* __restrict__ Tin, ushort* __restrict__ Pp, int step)
{
    __shared__ __align__(16) ushort smem[8*640 + 16*648];
    __shared__ float soft_s[8][9];
    ushort* sm_ms = smem;
    ushort* sm_t  = smem + 8*640;

    int bid    = blockIdx.x;
    int ks     = bid & (KS_-1);
    int rowblk = (bid >> 3) & 63;
    int b      = bid >> 9;
    int n0     = rowblk * 16;
    int tid    = threadIdx.x;
    int lane   = tid & 63;
    int w      = tid >> 6;

    if (tid < 8) {
        int h = tid;
        float vals[A_];
        float m = 0.0f;
        #pragma unroll
        for (int a = 0; a < A_; a++) {
            float v = kern[h*A_*P_ + a*P_ + step];
            v = v > 0.0f ? v : 0.0f;
            vals[a] = v;
            m = fmaxf(m, v);
        }
        float s = 0.0f;
        #pragma unroll
        for (int a = 0; a < A_; a++) { vals[a] = expf(vals[a] - m); s += vals[a]; }
        float inv = 1.0f / s;
        #pragma unroll
        for (int a = 0; a < A_; a++) soft_s[h][a] = vals[a] * inv;
    }
    __syncthreads();

    int mr   = tid >> 4;
    int mk2  = (tid & 15) * 2;
    int mk2s = mk2 ^ ((mr & 3) << 3);
    ushort* ablk = adjp + (size_t)((b*64 + rowblk)*8 + ks) * 18432;

    int sp  = tid >> 4;
    int sk0 = (tid & 15) * 2;
    const ushort* tbase = Tin + ((size_t)(b*16 + sp)*1024 + (size_t)ks*128) * 16;

    int g   = lane >> 4;
    int c15 = lane & 15;
    int gx  = (g ^ (c15 & 3)) * 8;

    f32x4 acc[4];
    #pragma unroll
    for (int j = 0; j < 4; j++) acc[j] = (f32x4){0.f, 0.f, 0.f, 0.f};

    for (int chunk = 0; chunk < 4; chunk++) {
        float lo[9], hi[9];
        if constexpr (PACK) {
            #pragma unroll
            for (int a = 0; a < A_; a++) {
                float2 v = *(const float2*)&adjf[(((size_t)b*A_ + a)*N_ + (n0+mr))*N_
                                                 + ks*128 + chunk*32 + mk2];
                lo[a] = v.x; hi[a] = v.y;
            }
        } else {
            #pragma unroll
            for (int a = 0; a < A_; a++) {
                uint av = *(const uint*)&ablk[chunk*4608 + (a*16 + mr)*32 + mk2];
                lo[a] = bflo(av); hi[a] = bfhi(av);
            }
        }
        const ushort* tsl = tbase + (size_t)(chunk*32 + sk0) * 16;
        uint4 q0 = *(const uint4*)(tsl + 0);
        uint4 q1 = *(const uint4*)(tsl + 8);
        uint4 q2 = *(const uint4*)(tsl + 16);
        uint4 q3 = *(const uint4*)(tsl + 24);

        if constexpr (PACK) {
            #pragma unroll
            for (int a = 0; a < A_; a++)
                *(uint*)&ablk[chunk*4608 + (a*16 + mr)*32 + mk2] = pack2_bf(lo[a], hi[a]);
        }

        if (chunk) __syncthreads();

        #pragma unroll
        for (int h = 0; h < H_; h++) {
            float s0 = soft_s[h][0]*lo[0];
            float s1 = soft_s[h][0]*hi[0];
            #pragma unroll
            for (int a = 1; a < A_; a++) { s0 += soft_s[h][a]*lo[a]; s1 += soft_s[h][a]*hi[a]; }
            *(uint*)&sm_ms[h*640 + mr*40 + mk2s] = pack2_bf(s0, s1);
        }
        {
            uint l0[4] = {q0.x, q0.y, q0.z, q0.w};
            uint l1[4] = {q1.x, q1.y, q1.z, q1.w};
            uint h0[4] = {q2.x, q2.y, q2.z, q2.w};
            uint h1[4] = {q3.x, q3.y, q3.z, q3.w};
            #pragma unroll
            for (int ci = 0; ci < 8; ci++) {
                uint a0 = (l0[ci>>1] >> ((ci&1)*16)) & 0xffffu;
                uint b0 = (h0[ci>>1] >> ((ci&1)*16)) & 0xffffu;
                int k0s = sk0 ^ ((ci & 3) << 3);
                *(uint*)&sm_t[sp*648 + ci*40 + k0s] = a0 | (b0 << 16);
            }
            #pragma unroll
            for (int ci = 0; ci < 8; ci++) {
                int c = ci + 8;
                uint a0 = (l1[ci>>1] >> ((ci&1)*16)) & 0xffffu;
                uint b0 = (h1[ci>>1] >> ((ci&1)*16)) & 0xffffu;
                int k0s = sk0 ^ ((c & 3) << 3);
                *(uint*)&sm_t[sp*648 + c*40 + k0s] = a0 | (b0 << 16);
            }
        }
        __syncthreads();

        {
            const ushort* mb = sm_ms + c15*40 + gx;
            const ushort* tb = sm_t  + c15*40 + gx;
            #pragma unroll
            for (int j = 0; j < 4; j++) {
                int cg = w + 4*j;
                int h  = cg >> 1;
                bf16x8 af  = *(const bf16x8*)&mb[h*640];
                bf16x8 bfr = *(const bf16x8*)&tb[cg*648];
                acc[j] = __builtin_amdgcn_mfma_f32_16x16x32_bf16(af, bfr, acc[j], 0, 0, 0);
            }
        }
    }

    __syncthreads();
    float* Ep = (float*)smem;
    #pragma unroll
    for (int j = 0; j < 4; j++) {
        int cg = w + 4*j;
        #pragma unroll
        for (int i = 0; i < 4; i++)
            Ep[cg*256 + (g*4 + i)*16 + c15] = acc[j][i];
    }
    __syncthreads();
    {
        int p = tid >> 4, r = tid & 15;
        ushort* dst = Pp + (((size_t)(ks*B_ + b)*16 + p)*N_ + (n0 + r)) * 16;
        const float* src = &Ep[p*256 + r*16];
        uint u0 = pack2_bf(src[0],  src[1]);
        uint u1 = pack2_bf(src[2],  src[3]);
        uint u2 = pack2_bf(src[4],  src[5]);
        uint u3 = pack2_bf(src[6],  src[7]);
        uint u4 = pack2_bf(src[8],  src[9]);
        uint u5 = pack2_bf(src[10], src[11]);
        uint u6 = pack2_bf(src[12], src[13]);
        uint u7 = pack2_bf(src[14], src[15]);
        *(uint4*)&dst[0] = make_uint4(u0,u1,u2,u3);
        *(uint4*)&dst[8] = make_uint4(u4,u5,u6,u7);
    }
}

// ---------------- reduce KS_ bf16 slabs -> bf16 T panels (fp32 accumulate) ----------------
__global__ void chain_reduce(const ushort* __restrict__ Pp, ushort* __restrict__ outp)
{
    int pidx = blockIdx.x * 256 + threadIdx.x;   // one uint2 (4 bf16) per thread
    float4 s = make_float4(0.f, 0.f, 0.f, 0.f);
    #pragma unroll
    for (int ks = 0; ks < KS_; ks++) {
        uint2 v = ((const uint2*)Pp)[(size_t)ks*SLABU2_ + pidx];
        s.x += bflo(v.x); s.y += bfhi(v.x);
        s.z += bflo(v.y); s.w += bfhi(v.y);
    }
    uint2 wv;
    wv.x = pack2_bf(s.x, s.y);
    wv.y = pack2_bf(s.z, s.w);
    ((uint2*)outp)[pidx] = wv;
}

// ---------------- V projection (SIMT, writes bf16 panels) ----------------
#define BK 16
__global__ void gemm_v(const float* __restrict__ A, const float* __restrict__ Bm,
                       const float* __restrict__ bias, ushort* __restrict__ C)
{
    __shared__ __align__(16) float As[BK][68];
    __shared__ __align__(16) float Bs[BK][68];
    int m0 = blockIdx.x * 64;
    int n0 = blockIdx.y * 64;
    int tid = threadIdx.x;
    int tx = tid & 15, ty = tid >> 4;

    float acc[4][4];
    #pragma unroll
    for (int i = 0; i < 4; i++)
        #pragma unroll
        for (int j = 0; j < 4; j++) acc[i][j] = 0.0f;

    for (int k0 = 0; k0 < D_; k0 += BK) {
        {
            int m = tid >> 2;
            int k = (tid & 3) * 4;
            float4 v = *(const float4*)&A[(size_t)(m0+m)*D_ + k0 + k];
            As[k+0][m] = v.x; As[k+1][m] = v.y; As[k+2][m] = v.z; As[k+3][m] = v.w;
        }
        {
            int k = tid >> 4;
            int n = (tid & 15) * 4;
            int c = n0 + n; int h = c >> 5; int ee = c & 31;
            float4 v = *(const float4*)&Bm[(size_t)h*D_*DH_ + (size_t)(k0+k)*DH_ + ee];
            *(float4*)&Bs[k][n] = v;
        }
        __syncthreads();
        #pragma unroll
        for (int k = 0; k < BK; k++) {
            float4 a4 = *(const float4*)&As[k][ty*4];
            float4 b4 = *(const float4*)&Bs[k][tx*4];
            acc[0][0] += a4.x*b4.x; acc[0][1] += a4.x*b4.y; acc[0][2] += a4.x*b4.z; acc[0][3] += a4.x*b4.w;
            acc[1][0] += a4.y*b4.x; acc[1][1] += a4.y*b4.y; acc[1][2] += a4.y*b4.z; acc[1][3] += a4.y*b4.w;
            acc[2][0] += a4.z*b4.x; acc[2][1] += a4.z*b4.y; acc[2][2] += a4.z*b4.z; acc[2][3] += a4.z*b4.w;
            acc[3][0] += a4.w*b4.x; acc[3][1] += a4.w*b4.y; acc[3][2] += a4.w*b4.z; acc[3][3] += a4.w*b4.w;
        }
        __syncthreads();
    }

    #pragma unroll
    for (int i = 0; i < 4; i++) {
        int row  = m0 + ty*4 + i;
        int nloc = n0 + tx*4;
        float o[4];
        #pragma unroll
        for (int j = 0; j < 4; j++) {
            int c = nloc + j;
            int h = c >> 5, ee = c & 31, n = row & (N_-1);
            o[j] = acc[i][j] + bias[(size_t)h*N_*DH_ + (size_t)n*DH_ + ee];
        }
        int bb = row >> 10, n = row & (N_-1);
        int cg = nloc >> 4, cc = nloc & 15;
        uint2 wv;
        wv.x = pack2_bf(o[0], o[1]);
        wv.y = pack2_bf(o[2], o[3]);
        *(uint2*)&C[(((size_t)bb*16 + cg)*N_ + n)*16 + cc] = wv;
    }
}

// ================= FFN tail: BM=8, grid 256, 256 threads =================

// ---- gemm_r: attn(=sum bf16 Pp slabs * 1/diag(degree)) @ W0 + x -> resid(fp32); h=LN -> hbuf ----
__global__ __launch_bounds__(256, 4)
void gemm_r(const ushort* __restrict__ Pp, const float* __restrict__ degree,
            const float* __restrict__ W0, const float* __restrict__ x,
            const float* __restrict__ gamma, const float* __restrict__ beta,
            float* __restrict__ resid, ushort* __restrict__ hbuf)
{
    __shared__ __align__(16) ushort As[16*40];
    __shared__ __align__(16) ushort Bs[256*40];
    __shared__ float lnb[8*257];
    __shared__ float2 stat[8];

    int m0 = blockIdx.x * 8;
    int b  = m0 >> 10;
    int nb = m0 & (N_-1);
    int tid = threadIdx.x;
    int lane = tid & 63;
    int w = tid >> 6;
    int g = lane >> 4, c15 = lane & 15;
    int gx = (g ^ (c15 & 3)) * 8;

    int am  = tid >> 4;
    int ak2 = (tid & 15) * 2;
    int apos = am*40 + ((((ak2>>3) ^ (am&3))) << 3) + (ak2 & 7);
    float idv = 0.f;
    if (tid < 128) {
        int n = nb + am;
        idv = 1.0f / degree[((size_t)b*N_ + n)*N_ + n];
    }

    int bn8 = (tid & 31) * 8;
    int bkq = (tid >> 5) * 4;
    int bposR = ((bkq >> 3) << 3) + (bkq & 7);

    f32x4 acc[4];
    #pragma unroll
    for (int j = 0; j < 4; j++) acc[j] = (f32x4){0.f,0.f,0.f,0.f};

    for (int ksi = 0; ksi < 8; ksi++) {
        int k0 = ksi * 32;
        uint av = 0;
        if (tid < 128) {
            int k = k0 + ak2;
            size_t base = (((size_t)(b*16 + (k>>4)))*N_ + nb + am)*16 + (k & 15);
            float s0 = 0.f, s1 = 0.f;
            #pragma unroll
            for (int sl = 0; sl < 8; sl++) {
                uint v = *(const uint*)&Pp[(size_t)sl*SLABU_ + base];
                s0 += bflo(v); s1 += bfhi(v);
            }
            av = pack2_bf(s0*idv, s1*idv);
        }
        float4 lo[4], hi[4];
        #pragma unroll
        for (int i = 0; i < 4; i++) {
            lo[i] = *(const float4*)&W0[(size_t)(k0+bkq+i)*D_ + bn8];
            hi[i] = *(const float4*)&W0[(size_t)(k0+bkq+i)*D_ + bn8 + 4];
        }
        if (ksi) __syncthreads();
        if (tid < 128) *(uint*)&As[apos] = av;
        #pragma unroll
        for (int jn = 0; jn < 8; jn++) {
            int n = bn8 + jn;
            float v0 = (jn<4)? ((const float*)&lo[0])[jn] : ((const float*)&hi[0])[jn-4];
            float v1 = (jn<4)? ((const float*)&lo[1])[jn] : ((const float*)&hi[1])[jn-4];
            float v2 = (jn<4)? ((const float*)&lo[2])[jn] : ((const float*)&hi[2])[jn-4];
            float v3 = (jn<4)? ((const float*)&lo[3])[jn] : ((const float*)&hi[3])[jn-4];
            uint2 wv; wv.x = pack2_bf(v0, v1); wv.y = pack2_bf(v2, v3);
            *(uint2*)&Bs[n*40 + (bposR ^ ((n&3)<<3))] = wv;
        }
        __syncthreads();
        const ushort* ab = As + c15*40 + gx;
        #pragma unroll
        for (int nt = 0; nt < 4; nt++) {
            int n = w*64 + nt*16 + c15;
            bf16x8 af  = *(const bf16x8*)ab;
            bf16x8 bfr = *(const bf16x8*)&Bs[n*40 + gx];
            acc[nt] = __builtin_amdgcn_mfma_f32_16x16x32_bf16(af, bfr, acc[nt], 0, 0, 0);
        }
    }
    __syncthreads();

    if (g < 2) {
        #pragma unroll
        for (int nt = 0; nt < 4; nt++) {
            int c = w*64 + nt*16 + c15;
            #pragma unroll
            for (int i = 0; i < 4; i++) {
                int r = g*4 + i;
                lnb[r*257 + c] = acc[nt][i] + x[(size_t)(m0+r)*D_ + c];
            }
        }
    }
    __syncthreads();
    if (tid < 128) {
        int rr = tid >> 4, sl = tid & 15;
        float sum = 0.f, sq = 0.f;
        #pragma unroll
        for (int j = 0; j < 16; j++) {
            float v = lnb[rr*257 + sl + 16*j];
            sum += v; sq += v*v;
        }
        #pragma unroll
        for (int m = 1; m < 16; m <<= 1) { sum += __shfl_xor(sum, m); sq += __shfl_xor(sq, m); }
        if (sl == 0) {
            float mean = sum * (1.0f/D_);
            float var  = fmaxf(sq * (1.0f/D_) - mean*mean, 0.f);
            stat[rr] = make_float2(mean, rsqrtf(var + 1e-12f));
        }
    }
    __syncthreads();
    if (tid < 128) {
        int rr = tid & 7, s2 = tid >> 3;
        float2 ms = stat[rr];
        int c0 = s2 * 16;
        uint hw[8];
        #pragma unroll
        for (int q = 0; q < 4; q++) {
            int c = c0 + q*4;
            float4 v = *(const float4*)&lnb[rr*257 + c];
            *(float4*)&resid[(size_t)(m0+rr)*D_ + c] = v;
            float4 gm = *(const float4*)&gamma[c];
            float4 bt = *(const float4*)&beta[c];
            float h0 = (v.x - ms.x)*ms.y*gm.x + bt.x;
            float h1 = (v.y - ms.x)*ms.y*gm.y + bt.y;
            float h2 = (v.z - ms.x)*ms.y*gm.z + bt.z;
            float h3 = (v.w - ms.x)*ms.y*gm.w + bt.w;
            hw[2*q]   = pack2_bf(h0, h1);
            hw[2*q+1] = pack2_bf(h2, h3);
        }
        ushort* hp = &hbuf[(size_t)(m0+rr)*D_ + c0];
        *(uint4*)&hp[0] = make_uint4(hw[0], hw[1], hw[2], hw[3]);
        *(uint4*)&hp[8] = make_uint4(hw[4], hw[5], hw[6], hw[7]);
    }
}

// ---- gemm_f1: f = LN(gelu(h@W1 + b1), gf, bf) -> bf16 global ----
__global__ __launch_bounds__(256, 2)
void gemm_f1(const ushort* __restrict__ hbuf, const float* __restrict__ W1,
             const float* __restrict__ b1, const float* __restrict__ gf,
             const float* __restrict__ bfv, ushort* __restrict__ fout)
{
    __shared__ __align__(16) ushort As[16*40];
    __shared__ __align__(16) ushort Bs[512*40];
    __shared__ float lnb[8*513];
    __shared__ float2 stat[8];

    int m0 = blockIdx.x * 8;
    int tid = threadIdx.x;
    int lane = tid & 63;
    int w = tid >> 6;
    int g = lane >> 4, c15 = lane & 15;
    int gx = (g ^ (c15 & 3)) * 8;

    int am  = tid >> 4;
    int ak2 = (tid & 15) * 2;
    int apos = am*40 + ((((ak2>>3) ^ (am&3))) << 3) + (ak2 & 7);
    int bn8 = (tid & 63) * 8;
    int bk8 = (tid >> 6) * 8;

    f32x4 acc1[8];
    #pragma unroll
    for (int j = 0; j < 8; j++) acc1[j] = (f32x4){0.f,0.f,0.f,0.f};

    for (int ksi = 0; ksi < 8; ksi++) {
        int k0 = ksi * 32;
        uint av = 0;
        if (tid < 128) av = *(const uint*)&hbuf[(size_t)(m0+am)*D_ + k0 + ak2];
        float4 q[16];
        #pragma unroll
        for (int i = 0; i < 8; i++) {
            q[2*i]   = *(const float4*)&W1[(size_t)(k0+bk8+i)*(2*D_) + bn8];
            q[2*i+1] = *(const float4*)&W1[(size_t)(k0+bk8+i)*(2*D_) + bn8 + 4];
        }
        if (ksi) __syncthreads();
        if (tid < 128) *(uint*)&As[apos] = av;
        #pragma unroll
        for (int jn = 0; jn < 8; jn++) {
            int n = bn8 + jn;
            float e0 = (jn<4)? ((const float*)&q[0])[jn]  : ((const float*)&q[1])[jn-4];
            float e1 = (jn<4)? ((const float*)&q[2])[jn]  : ((const float*)&q[3])[jn-4];
            float e2 = (jn<4)? ((const float*)&q[4])[jn]  : ((const float*)&q[5])[jn-4];
            float e3 = (jn<4)? ((const float*)&q[6])[jn]  : ((const float*)&q[7])[jn-4];
            float e4 = (jn<4)? ((const float*)&q[8])[jn]  : ((const float*)&q[9])[jn-4];
            float e5 = (jn<4)? ((const float*)&q[10])[jn] : ((const float*)&q[11])[jn-4];
            float e6 = (jn<4)? ((const float*)&q[12])[jn] : ((const float*)&q[13])[jn-4];
            float e7 = (jn<4)? ((const float*)&q[14])[jn] : ((const float*)&q[15])[jn-4];
            uint4 wv;
            wv.x = pack2_bf(e0, e1); wv.y = pack2_bf(e2, e3);
            wv.z = pack2_bf(e4, e5); wv.w = pack2_bf(e6, e7);
            *(uint4*)&Bs[n*40 + ((((bk8>>3) ^ (n&3))) << 3)] = wv;
        }
        __syncthreads();
        const ushort* ab = As + c15*40 + gx;
        #pragma unroll
        for (int nt = 0; nt < 8; nt++) {
            int n = w*128 + nt*16 + c15;
            bf16x8 af  = *(const bf16x8*)ab;
            bf16x8 bfr = *(const bf16x8*)&Bs[n*40 + gx];
            acc1[nt] = __builtin_amdgcn_mfma_f32_16x16x32_bf16(af, bfr, acc1[nt], 0, 0, 0);
        }
    }
    __syncthreads();

    if (g < 2) {
        #pragma unroll
        for (int nt = 0; nt < 8; nt++) {
            int c = w*128 + nt*16 + c15;
            float bias = b1[c];
            #pragma unroll
            for (int i = 0; i < 4; i++) {
                int r = g*4 + i;
                float v = acc1[nt][i] + bias;
                v = 0.5f * v * (1.0f + erff(v * 0.70710678118654752f));
                lnb[r*513 + c] = v;
            }
        }
    }
    __syncthreads();
    if (tid < 128) {
        int rr = tid >> 4, sl = tid & 15;
        float sum = 0.f, sq = 0.f;
        #pragma unroll
        for (int j = 0; j < 32; j++) {
            float v = lnb[rr*513 + sl + 16*j];
            sum += v; sq += v*v;
        }
        #pragma unroll
        for (int m = 1; m < 16; m <<= 1) { sum += __shfl_xor(sum, m); sq += __shfl_xor(sq, m); }
        if (sl == 0) {
            float mean = sum * (1.0f/(2*D_));
            float var  = fmaxf(sq * (1.0f/(2*D_)) - mean*mean, 0.f);
            stat[rr] = make_float2(mean, rsqrtf(var + 1e-12f));
        }
    }
    __syncthreads();
    if (tid < 128) {
        int rr = tid & 7, s2 = tid >> 3;
        float2 ms = stat[rr];
        int c0 = s2 * 32;
        #pragma unroll
        for (int q = 0; q < 8; q++) {
            int c = c0 + q*4;
            float4 v = *(const float4*)&lnb[rr*513 + c];
            float4 gm = *(const float4*)&gf[c];
            float4 bt = *(const float4*)&bfv[c];
            float h0 = (v.x - ms.x)*ms.y*gm.x + bt.x;
            float h1 = (v.y - ms.x)*ms.y*gm.y + bt.y;
            float h2 = (v.z - ms.x)*ms.y*gm.z + bt.z;
            float h3 = (v.w - ms.x)*ms.y*gm.w + bt.w;
            *(uint2*)&fout[(size_t)(m0+rr)*(2*D_) + c] = make_uint2(pack2_bf(h0,h1), pack2_bf(h2,h3));
        }
    }
}

// ---- gemm_f2: out = f@W2 + b2f + resid ----
__global__ __launch_bounds__(256, 4)
void gemm_f2(const ushort* __restrict__ fbuf, const float* __restrict__ W2,
             const float* __restrict__ b2f, const float* __restrict__ resid,
             float* __restrict__ outp)
{
    __shared__ __align__(16) ushort As[16*40];
    __shared__ __align__(16) ushort Bs[256*40];
    __shared__ float esc[8*257];

    int m0 = blockIdx.x * 8;
    int tid = threadIdx.x;
    int lane = tid & 63;
    int w = tid >> 6;
    int g = lane >> 4, c15 = lane & 15;
    int gx = (g ^ (c15 & 3)) * 8;

    int am  = tid >> 4;
    int ak2 = (tid & 15) * 2;
    int apos = am*40 + ((((ak2>>3) ^ (am&3))) << 3) + (ak2 & 7);
    int bn8 = (tid & 31) * 8;
    int bkq = (tid >> 5) * 4;
    int bposR = ((bkq >> 3) << 3) + (bkq & 7);

    f32x4 acc[4];
    #pragma unroll
    for (int j = 0; j < 4; j++) acc[j] = (f32x4){0.f,0.f,0.f,0.f};

    for (int ksi = 0; ksi < 16; ksi++) {
        int k0 = ksi * 32;
        uint av = 0;
        if (tid < 128) av = *(const uint*)&fbuf[(size_t)(m0+am)*(2*D_) + k0 + ak2];
        float4 lo[4], hi[4];
        #pragma unroll
        for (int i = 0; i < 4; i++) {
            lo[i] = *(const float4*)&W2[(size_t)(k0+bkq+i)*D_ + bn8];
            hi[i] = *(const float4*)&W2[(size_t)(k0+bkq+i)*D_ + bn8 + 4];
        }
        if (ksi) __syncthreads();
        if (tid < 128) *(uint*)&As[apos] = av;
        #pragma unroll
        for (int jn = 0; jn < 8; jn++) {
            int n = bn8 + jn;
            float v0 = (jn<4)? ((const float*)&lo[0])[jn] : ((const float*)&hi[0])[jn-4];
            float v1 = (jn<4)? ((const float*)&lo[1])[jn] : ((const float*)&hi[1])[jn-4];
            float v2 = (jn<4)? ((const float*)&lo[2])[jn] : ((const float*)&hi[2])[jn-4];
            float v3 = (jn<4)? ((const float*)&lo[3])[jn] : ((const float*)&hi[3])[jn-4];
            uint2 wv; wv.x = pack2_bf(v0, v1); wv.y = pack2_bf(v2, v3);
            *(uint2*)&Bs[n*40 + (bposR ^ ((n&3)<<3))] = wv;
        }
        __syncthreads();
        const ushort* ab = As + c15*40 + gx;
        #pragma unroll
        for (int nt = 0; nt < 4; nt++) {
            int n = w*64 + nt*16 + c15;
            bf16x8 af  = *(const bf16x8*)ab;
            bf16x8 bfr = *(const bf16x8*)&Bs[n*40 + gx];
            acc[nt] = __builtin_amdgcn_mfma_f32_16x16x32_bf16(af, bfr, acc[nt], 0, 0, 0);
        }
    }
    __syncthreads();

    if (g < 2) {
        #pragma unroll
        for (int nt = 0; nt < 4; nt++) {
            int c = w*64 + nt*16 + c15;
            #pragma unroll
            for (int i = 0; i < 4; i++)
                esc[(g*4+i)*257 + c] = acc[nt][i];
        }
    }
    __syncthreads();
    if (tid < 128) {
        int rr = tid & 7, s2 = tid >> 3;
        int c0 = s2 * 16;
        #pragma unroll
        for (int q = 0; q < 4; q++) {
            int c = c0 + q*4;
            float4 v  = *(const float4*)&esc[rr*257 + c];
            float4 bb = *(const float4*)&b2f[c];
            float4 rs = *(const float4*)&resid[(size_t)(m0+rr)*D_ + c];
            float4 o = make_float4(v.x+bb.x+rs.x, v.y+bb.y+rs.y, v.z+bb.z+rs.z, v.w+bb.w+rs.w);
            *(float4*)&outp[(size_t)(m0+rr)*D_ + c] = o;
        }
    }
}

extern "C" void kernel_launch(void* const* d_in, const int* in_sizes, int n_in,
                              void* d_out, int out_size, void* d_ws, size_t ws_size,
                              hipStream_t stream)
{
    const float* adj    = (const float*)d_in[0];
    const float* degree = (const float*)d_in[1];
    const float* x      = (const float*)d_in[2];
    const float* kern   = (const float*)d_in[3];
    const float* Wv     = (const float*)d_in[4];
    const float* Bv     = (const float*)d_in[5];
    const float* W0     = (const float*)d_in[6];
    const float* gamma2 = (const float*)d_in[7];
    const float* beta2  = (const float*)d_in[8];
    const float* W1     = (const float*)d_in[9];
    const float* b1     = (const float*)d_in[10];
    const float* gf     = (const float*)d_in[11];
    const float* bf_    = (const float*)d_in[12];
    const float* W2     = (const float*)d_in[13];
    const float* b2f    = (const float*)d_in[14];
    float* out = (float*)d_out;
    float* ws  = (float*)d_ws;

    size_t off = 0;
    float* T0    = ws + off; off += (size_t)ROWS_*D_/2;     // bf16 panels (1MB)
    float* T1    = ws + off; off += (size_t)ROWS_*D_/2;
    float* resid = ws + off; off += (size_t)ROWS_*D_;       // fp32
    float* hbufF = ws + off; off += (size_t)ROWS_*D_/2;     // bf16
    float* foutF = ws + off; off += (size_t)ROWS_*D_;       // bf16 (2D cols)
    float* PpF   = ws + off; off += (size_t)KS_*ROWS_*D_/2; // bf16 slabs (8MB)
    ushort* adjp = (ushort*)(ws + off);                      // 37.75MB bf16

    ushort* T0b = (ushort*)T0;
    ushort* T1b = (ushort*)T1;
    ushort* hb  = (ushort*)hbufF;
    ushort* fb  = (ushort*)foutF;
    ushort* Pp  = (ushort*)PpF;

    gemm_v<<<dim3(ROWS_/64, D_/64), 256, 0, stream>>>(x, Wv, Bv, T0b);

    int chain_grid  = B_*64*KS_;     // 1024
    int reduce_grid = SLABU2_/256;   // 512
    chain_mfma<1><<<chain_grid, 256, 0, stream>>>(adj, adjp, kern, T0b, Pp, 3);
    chain_reduce<<<reduce_grid, 256, 0, stream>>>(Pp, T1b);
    chain_mfma<0><<<chain_grid, 256, 0, stream>>>(adj, adjp, kern, T1b, Pp, 2);
    chain_reduce<<<reduce_grid, 256, 0, stream>>>(Pp, T0b);
    chain_mfma<0><<<chain_grid, 256, 0, stream>>>(adj, adjp, kern, T0b, Pp, 1);
    chain_reduce<<<reduce_grid, 256, 0, stream>>>(Pp, T1b);
    chain_mfma<0><<<chain_grid, 256, 0, stream>>>(adj, adjp, kern, T1b, Pp, 0);

    gemm_r <<<ROWS_/8, 256, 0, stream>>>(Pp, degree, W0, x, gamma2, beta2, resid, hb);
    gemm_f1<<<ROWS_/8, 256, 0, stream>>>(hb, W1, b1, gf, bf_, fb);
    gemm_f2<<<ROWS_/8, 256, 0, stream>>>(fb, W2, b2f, resid, out);
}

// Round 14
// 163.330 us; speedup vs baseline: 7.9663x; 1.0234x over previous
//
#include <hip/hip_runtime.h>
#include <hip/hip_bf16.h>
#include <math.h>

#define B_ 2
#define A_ 9
#define N_ 1024
#define P_ 4
#define D_ 256
#define H_ 8
#define DH_ 32
#define ROWS_ (B_*N_)   // 2048
#define KS_ 8           // K-split factor for chain (k-slice 128)
#define SLABU_ 524288   // Pp slab stride in ushorts (2*16*1024*16)
#define SLABU2_ 131072  // Pp slab stride in uint2 (4 bf16 each)

typedef __attribute__((ext_vector_type(8))) short bf16x8;
typedef __attribute__((ext_vector_type(4))) float f32x4;

__device__ __forceinline__ uint pack2_bf(float x, float y) {
    uint ux = __float_as_uint(x); ux += 0x7fffu + ((ux >> 16) & 1u);
    uint uy = __float_as_uint(y); uy += 0x7fffu + ((uy >> 16) & 1u);
    return (ux >> 16) | (uy & 0xffff0000u);
}
__device__ __forceinline__ float bflo(uint u){ return __uint_as_float(u << 16); }
__device__ __forceinline__ float bfhi(uint u){ return __uint_as_float(u & 0xffff0000u); }

// ---------------- MFMA chain step. PACK=1: read fp32 adjacency + write bf16 adjp slab ----------------
template<int PACK>
__global__ __launch_bounds__(256, 4)
void chain_mfma(const float* __restrict__ adjf, ushort* __restrict__ adjp,
                const float* __restrict__ kern,
                const ushort* __restrict__ Tin, ushort* __restrict__ Pp, int step)
{
    __shared__ __align__(16) ushort smem[8*640 + 16*648];
    __shared__ float soft_s[8][9];
    ushort* sm_ms = smem;
    ushort* sm_t  = smem + 8*640;

    int bid    = blockIdx.x;
    int ks     = bid & (KS_-1);
    int rowblk = (bid >> 3) & 63;
    int b      = bid >> 9;
    int n0     = rowblk * 16;
    int tid    = threadIdx.x;
    int lane   = tid & 63;
    int w      = tid >> 6;

    if (tid < 8) {
        int h = tid;
        float vals[A_];
        float m = 0.0f;
        #pragma unroll
        for (int a = 0; a < A_; a++) {
            float v = kern[h*A_*P_ + a*P_ + step];
            v = v > 0.0f ? v : 0.0f;
            vals[a] = v;
            m = fmaxf(m, v);
        }
        float s = 0.0f;
        #pragma unroll
        for (int a = 0; a < A_; a++) { vals[a] = expf(vals[a] - m); s += vals[a]; }
        float inv = 1.0f / s;
        #pragma unroll
        for (int a = 0; a < A_; a++) soft_s[h][a] = vals[a] * inv;
    }
    __syncthreads();

    int mr   = tid >> 4;
    int mk2  = (tid & 15) * 2;
    int mk2s = mk2 ^ ((mr & 3) << 3);
    ushort* ablk = adjp + (size_t)((b*64 + rowblk)*8 + ks) * 18432;

    int sp  = tid >> 4;
    int sk0 = (tid & 15) * 2;
    const ushort* tbase = Tin + ((size_t)(b*16 + sp)*1024 + (size_t)ks*128) * 16;

    int g   = lane >> 4;
    int c15 = lane & 15;
    int gx  = (g ^ (c15 & 3)) * 8;

    f32x4 acc[4];
    #pragma unroll
    for (int j = 0; j < 4; j++) acc[j] = (f32x4){0.f, 0.f, 0.f, 0.f};

    for (int chunk = 0; chunk < 4; chunk++) {
        float lo[9], hi[9];
        if constexpr (PACK) {
            #pragma unroll
            for (int a = 0; a < A_; a++) {
                float2 v = *(const float2*)&adjf[(((size_t)b*A_ + a)*N_ + (n0+mr))*N_
                                                 + ks*128 + chunk*32 + mk2];
                lo[a] = v.x; hi[a] = v.y;
            }
        } else {
            #pragma unroll
            for (int a = 0; a < A_; a++) {
                uint av = *(const uint*)&ablk[chunk*4608 + (a*16 + mr)*32 + mk2];
                lo[a] = bflo(av); hi[a] = bfhi(av);
            }
        }
        const ushort* tsl = tbase + (size_t)(chunk*32 + sk0) * 16;
        uint4 q0 = *(const uint4*)(tsl + 0);
        uint4 q1 = *(const uint4*)(tsl + 8);
        uint4 q2 = *(const uint4*)(tsl + 16);
        uint4 q3 = *(const uint4*)(tsl + 24);

        if constexpr (PACK) {
            #pragma unroll
            for (int a = 0; a < A_; a++)
                *(uint*)&ablk[chunk*4608 + (a*16 + mr)*32 + mk2] = pack2_bf(lo[a], hi[a]);
        }

        if (chunk) __syncthreads();

        #pragma unroll
        for (int h = 0; h < H_; h++) {
            float s0 = soft_s[h][0]*lo[0];
            float s1 = soft_s[h][0]*hi[0];
            #pragma unroll
            for (int a = 1; a < A_; a++) { s0 += soft_s[h][a]*lo[a]; s1 += soft_s[h][a]*hi[a]; }
            *(uint*)&sm_ms[h*640 + mr*40 + mk2s] = pack2_bf(s0, s1);
        }
        {
            uint l0[4] = {q0.x, q0.y, q0.z, q0.w};
            uint l1[4] = {q1.x, q1.y, q1.z, q1.w};
            uint h0[4] = {q2.x, q2.y, q2.z, q2.w};
            uint h1[4] = {q3.x, q3.y, q3.z, q3.w};
            #pragma unroll
            for (int ci = 0; ci < 8; ci++) {
                uint a0 = (l0[ci>>1] >> ((ci&1)*16)) & 0xffffu;
                uint b0 = (h0[ci>>1] >> ((ci&1)*16)) & 0xffffu;
                int k0s = sk0 ^ ((ci & 3) << 3);
                *(uint*)&sm_t[sp*648 + ci*40 + k0s] = a0 | (b0 << 16);
            }
            #pragma unroll
            for (int ci = 0; ci < 8; ci++) {
                int c = ci + 8;
                uint a0 = (l1[ci>>1] >> ((ci&1)*16)) & 0xffffu;
                uint b0 = (h1[ci>>1] >> ((ci&1)*16)) & 0xffffu;
                int k0s = sk0 ^ ((c & 3) << 3);
                *(uint*)&sm_t[sp*648 + c*40 + k0s] = a0 | (b0 << 16);
            }
        }
        __syncthreads();

        {
            const ushort* mb = sm_ms + c15*40 + gx;
            const ushort* tb = sm_t  + c15*40 + gx;
            #pragma unroll
            for (int j = 0; j < 4; j++) {
                int cg = w + 4*j;
                int h  = cg >> 1;
                bf16x8 af  = *(const bf16x8*)&mb[h*640];
                bf16x8 bfr = *(const bf16x8*)&tb[cg*648];
                acc[j] = __builtin_amdgcn_mfma_f32_16x16x32_bf16(af, bfr, acc[j], 0, 0, 0);
            }
        }
    }

    __syncthreads();
    float* Ep = (float*)smem;
    #pragma unroll
    for (int j = 0; j < 4; j++) {
        int cg = w + 4*j;
        #pragma unroll
        for (int i = 0; i < 4; i++)
            Ep[cg*256 + (g*4 + i)*16 + c15] = acc[j][i];
    }
    __syncthreads();
    {
        int p = tid >> 4, r = tid & 15;
        ushort* dst = Pp + (((size_t)(ks*B_ + b)*16 + p)*N_ + (n0 + r)) * 16;
        const float* src = &Ep[p*256 + r*16];
        uint u0 = pack2_bf(src[0],  src[1]);
        uint u1 = pack2_bf(src[2],  src[3]);
        uint u2 = pack2_bf(src[4],  src[5]);
        uint u3 = pack2_bf(src[6],  src[7]);
        uint u4 = pack2_bf(src[8],  src[9]);
        uint u5 = pack2_bf(src[10], src[11]);
        uint u6 = pack2_bf(src[12], src[13]);
        uint u7 = pack2_bf(src[14], src[15]);
        *(uint4*)&dst[0] = make_uint4(u0,u1,u2,u3);
        *(uint4*)&dst[8] = make_uint4(u4,u5,u6,u7);
    }
}

// ---------------- reduce KS_ bf16 slabs -> bf16 T panels (fp32 accumulate) ----------------
__global__ void chain_reduce(const ushort* __restrict__ Pp, ushort* __restrict__ outp)
{
    int pidx = blockIdx.x * 256 + threadIdx.x;   // one uint2 (4 bf16) per thread
    float4 s = make_float4(0.f, 0.f, 0.f, 0.f);
    #pragma unroll
    for (int ks = 0; ks < KS_; ks++) {
        uint2 v = ((const uint2*)Pp)[(size_t)ks*SLABU2_ + pidx];
        s.x += bflo(v.x); s.y += bfhi(v.x);
        s.z += bflo(v.y); s.w += bfhi(v.y);
    }
    uint2 wv;
    wv.x = pack2_bf(s.x, s.y);
    wv.y = pack2_bf(s.z, s.w);
    ((uint2*)outp)[pidx] = wv;
}

// ---------------- V projection (MFMA, BM=8, grid 256): T = x @ Wv(cat) + Bv -> bf16 panels ----------------
__global__ __launch_bounds__(256, 4)
void gemm_v(const float* __restrict__ x, const float* __restrict__ Wv,
            const float* __restrict__ Bv, ushort* __restrict__ C)
{
    __shared__ __align__(16) ushort As[16*40];
    __shared__ __align__(16) ushort Bs[256*40];
    __shared__ float lnb[8*257];

    int m0 = blockIdx.x * 8;
    int b  = m0 >> 10;
    int tid = threadIdx.x;
    int lane = tid & 63;
    int w = tid >> 6;
    int g = lane >> 4, c15 = lane & 15;
    int gx = (g ^ (c15 & 3)) * 8;

    int am  = tid >> 4;               // 0..7 valid when tid<128
    int ak2 = (tid & 15) * 2;
    int apos = am*40 + ((((ak2>>3) ^ (am&3))) << 3) + (ak2 & 7);

    int bn8 = (tid & 31) * 8;         // 8-col group, lies within one head
    int hh  = bn8 >> 5;
    int e0  = bn8 & 31;
    int bkq = (tid >> 5) * 4;
    int bposR = ((bkq >> 3) << 3) + (bkq & 7);

    f32x4 acc[4];
    #pragma unroll
    for (int j = 0; j < 4; j++) acc[j] = (f32x4){0.f,0.f,0.f,0.f};

    for (int ksi = 0; ksi < 8; ksi++) {
        int k0 = ksi * 32;
        uint av = 0;
        if (tid < 128) {
            float2 xv = *(const float2*)&x[(size_t)(m0+am)*D_ + k0 + ak2];
            av = pack2_bf(xv.x, xv.y);
        }
        float4 lo[4], hi[4];
        #pragma unroll
        for (int i = 0; i < 4; i++) {
            lo[i] = *(const float4*)&Wv[(size_t)hh*D_*DH_ + (size_t)(k0+bkq+i)*DH_ + e0];
            hi[i] = *(const float4*)&Wv[(size_t)hh*D_*DH_ + (size_t)(k0+bkq+i)*DH_ + e0 + 4];
        }
        if (ksi) __syncthreads();
        if (tid < 128) *(uint*)&As[apos] = av;
        #pragma unroll
        for (int jn = 0; jn < 8; jn++) {
            int n = bn8 + jn;
            float v0 = (jn<4)? ((const float*)&lo[0])[jn] : ((const float*)&hi[0])[jn-4];
            float v1 = (jn<4)? ((const float*)&lo[1])[jn] : ((const float*)&hi[1])[jn-4];
            float v2 = (jn<4)? ((const float*)&lo[2])[jn] : ((const float*)&hi[2])[jn-4];
            float v3 = (jn<4)? ((const float*)&lo[3])[jn] : ((const float*)&hi[3])[jn-4];
            uint2 wv; wv.x = pack2_bf(v0, v1); wv.y = pack2_bf(v2, v3);
            *(uint2*)&Bs[n*40 + (bposR ^ ((n&3)<<3))] = wv;
        }
        __syncthreads();
        const ushort* ab = As + c15*40 + gx;
        #pragma unroll
        for (int nt = 0; nt < 4; nt++) {
            int n = w*64 + nt*16 + c15;
            bf16x8 af  = *(const bf16x8*)ab;
            bf16x8 bfr = *(const bf16x8*)&Bs[n*40 + gx];
            acc[nt] = __builtin_amdgcn_mfma_f32_16x16x32_bf16(af, bfr, acc[nt], 0, 0, 0);
        }
    }
    __syncthreads();

    if (g < 2) {
        #pragma unroll
        for (int nt = 0; nt < 4; nt++) {
            int c = w*64 + nt*16 + c15;
            #pragma unroll
            for (int i = 0; i < 4; i++)
                lnb[(g*4+i)*257 + c] = acc[nt][i];
        }
    }
    __syncthreads();
    if (tid < 128) {
        int rr = tid & 7, s2 = tid >> 3;       // s2 = panel cg (0..15)
        int n  = (m0 + rr) & (N_-1);
        int c0 = s2 * 16;
        int h  = c0 >> 5;
        int eb = c0 & 31;                       // 0 or 16
        uint hw[8];
        #pragma unroll
        for (int q = 0; q < 4; q++) {
            int c = c0 + q*4;
            float4 v  = *(const float4*)&lnb[rr*257 + c];
            float4 bv = *(const float4*)&Bv[((size_t)h*N_ + n)*DH_ + eb + q*4];
            float o0 = v.x + bv.x;
            float o1 = v.y + bv.y;
            float o2 = v.z + bv.z;
            float o3 = v.w + bv.w;
            hw[2*q]   = pack2_bf(o0, o1);
            hw[2*q+1] = pack2_bf(o2, o3);
        }
        ushort* dst = &C[(((size_t)b*16 + s2)*N_ + n)*16];
        *(uint4*)&dst[0] = make_uint4(hw[0], hw[1], hw[2], hw[3]);
        *(uint4*)&dst[8] = make_uint4(hw[4], hw[5], hw[6], hw[7]);
    }
}

// ================= FFN tail: BM=8, grid 256, 256 threads =================

// ---- gemm_r: attn(=sum bf16 Pp slabs * 1/diag(degree)) @ W0 + x -> resid(fp32); h=LN -> hbuf ----
__global__ __launch_bounds__(256, 4)
void gemm_r(const ushort* __restrict__ Pp, const float* __restrict__ degree,
            const float* __restrict__ W0, const float* __restrict__ x,
            const float* __restrict__ gamma, const float* __restrict__ beta,
            float* __restrict__ resid, ushort* __restrict__ hbuf)
{
    __shared__ __align__(16) ushort As[16*40];
    __shared__ __align__(16) ushort Bs[256*40];
    __shared__ float lnb[8*257];
    __shared__ float2 stat[8];

    int m0 = blockIdx.x * 8;
    int b  = m0 >> 10;
    int nb = m0 & (N_-1);
    int tid = threadIdx.x;
    int lane = tid & 63;
    int w = tid >> 6;
    int g = lane >> 4, c15 = lane & 15;
    int gx = (g ^ (c15 & 3)) * 8;

    int am  = tid >> 4;
    int ak2 = (tid & 15) * 2;
    int apos = am*40 + ((((ak2>>3) ^ (am&3))) << 3) + (ak2 & 7);
    float idv = 0.f;
    if (tid < 128) {
        int n = nb + am;
        idv = 1.0f / degree[((size_t)b*N_ + n)*N_ + n];
    }

    int bn8 = (tid & 31) * 8;
    int bkq = (tid >> 5) * 4;
    int bposR = ((bkq >> 3) << 3) + (bkq & 7);

    f32x4 acc[4];
    #pragma unroll
    for (int j = 0; j < 4; j++) acc[j] = (f32x4){0.f,0.f,0.f,0.f};

    for (int ksi = 0; ksi < 8; ksi++) {
        int k0 = ksi * 32;
        uint av = 0;
        if (tid < 128) {
            int k = k0 + ak2;
            size_t base = (((size_t)(b*16 + (k>>4)))*N_ + nb + am)*16 + (k & 15);
            float s0 = 0.f, s1 = 0.f;
            #pragma unroll
            for (int sl = 0; sl < 8; sl++) {
                uint v = *(const uint*)&Pp[(size_t)sl*SLABU_ + base];
                s0 += bflo(v); s1 += bfhi(v);
            }
            av = pack2_bf(s0*idv, s1*idv);
        }
        float4 lo[4], hi[4];
        #pragma unroll
        for (int i = 0; i < 4; i++) {
            lo[i] = *(const float4*)&W0[(size_t)(k0+bkq+i)*D_ + bn8];
            hi[i] = *(const float4*)&W0[(size_t)(k0+bkq+i)*D_ + bn8 + 4];
        }
        if (ksi) __syncthreads();
        if (tid < 128) *(uint*)&As[apos] = av;
        #pragma unroll
        for (int jn = 0; jn < 8; jn++) {
            int n = bn8 + jn;
            float v0 = (jn<4)? ((const float*)&lo[0])[jn] : ((const float*)&hi[0])[jn-4];
            float v1 = (jn<4)? ((const float*)&lo[1])[jn] : ((const float*)&hi[1])[jn-4];
            float v2 = (jn<4)? ((const float*)&lo[2])[jn] : ((const float*)&hi[2])[jn-4];
            float v3 = (jn<4)? ((const float*)&lo[3])[jn] : ((const float*)&hi[3])[jn-4];
            uint2 wv; wv.x = pack2_bf(v0, v1); wv.y = pack2_bf(v2, v3);
            *(uint2*)&Bs[n*40 + (bposR ^ ((n&3)<<3))] = wv;
        }
        __syncthreads();
        const ushort* ab = As + c15*40 + gx;
        #pragma unroll
        for (int nt = 0; nt < 4; nt++) {
            int n = w*64 + nt*16 + c15;
            bf16x8 af  = *(const bf16x8*)ab;
            bf16x8 bfr = *(const bf16x8*)&Bs[n*40 + gx];
            acc[nt] = __builtin_amdgcn_mfma_f32_16x16x32_bf16(af, bfr, acc[nt], 0, 0, 0);
        }
    }
    __syncthreads();

    if (g < 2) {
        #pragma unroll
        for (int nt = 0; nt < 4; nt++) {
            int c = w*64 + nt*16 + c15;
            #pragma unroll
            for (int i = 0; i < 4; i++) {
                int r = g*4 + i;
                lnb[r*257 + c] = acc[nt][i] + x[(size_t)(m0+r)*D_ + c];
            }
        }
    }
    __syncthreads();
    if (tid < 128) {
        int rr = tid >> 4, sl = tid & 15;
        float sum = 0.f, sq = 0.f;
        #pragma unroll
        for (int j = 0; j < 16; j++) {
            float v = lnb[rr*257 + sl + 16*j];
            sum += v; sq += v*v;
        }
        #pragma unroll
        for (int m = 1; m < 16; m <<= 1) { sum += __shfl_xor(sum, m); sq += __shfl_xor(sq, m); }
        if (sl == 0) {
            float mean = sum * (1.0f/D_);
            float var  = fmaxf(sq * (1.0f/D_) - mean*mean, 0.f);
            stat[rr] = make_float2(mean, rsqrtf(var + 1e-12f));
        }
    }
    __syncthreads();
    if (tid < 128) {
        int rr = tid & 7, s2 = tid >> 3;
        float2 ms = stat[rr];
        int c0 = s2 * 16;
        uint hw[8];
        #pragma unroll
        for (int q = 0; q < 4; q++) {
            int c = c0 + q*4;
            float4 v = *(const float4*)&lnb[rr*257 + c];
            *(float4*)&resid[(size_t)(m0+rr)*D_ + c] = v;
            float4 gm = *(const float4*)&gamma[c];
            float4 bt = *(const float4*)&beta[c];
            float h0 = (v.x - ms.x)*ms.y*gm.x + bt.x;
            float h1 = (v.y - ms.x)*ms.y*gm.y + bt.y;
            float h2 = (v.z - ms.x)*ms.y*gm.z + bt.z;
            float h3 = (v.w - ms.x)*ms.y*gm.w + bt.w;
            hw[2*q]   = pack2_bf(h0, h1);
            hw[2*q+1] = pack2_bf(h2, h3);
        }
        ushort* hp = &hbuf[(size_t)(m0+rr)*D_ + c0];
        *(uint4*)&hp[0] = make_uint4(hw[0], hw[1], hw[2], hw[3]);
        *(uint4*)&hp[8] = make_uint4(hw[4], hw[5], hw[6], hw[7]);
    }
}

// ---- gemm_f1: f = LN(gelu(h@W1 + b1), gf, bf) -> bf16 global ----
__global__ __launch_bounds__(256, 2)
void gemm_f1(const ushort* __restrict__ hbuf, const float* __restrict__ W1,
             const float* __restrict__ b1, const float* __restrict__ gf,
             const float* __restrict__ bfv, ushort* __restrict__ fout)
{
    __shared__ __align__(16) ushort As[16*40];
    __shared__ __align__(16) ushort Bs[512*40];
    __shared__ float lnb[8*513];
    __shared__ float2 stat[8];

    int m0 = blockIdx.x * 8;
    int tid = threadIdx.x;
    int lane = tid & 63;
    int w = tid >> 6;
    int g = lane >> 4, c15 = lane & 15;
    int gx = (g ^ (c15 & 3)) * 8;

    int am  = tid >> 4;
    int ak2 = (tid & 15) * 2;
    int apos = am*40 + ((((ak2>>3) ^ (am&3))) << 3) + (ak2 & 7);
    int bn8 = (tid & 63) * 8;
    int bk8 = (tid >> 6) * 8;

    f32x4 acc1[8];
    #pragma unroll
    for (int j = 0; j < 8; j++) acc1[j] = (f32x4){0.f,0.f,0.f,0.f};

    for (int ksi = 0; ksi < 8; ksi++) {
        int k0 = ksi * 32;
        uint av = 0;
        if (tid < 128) av = *(const uint*)&hbuf[(size_t)(m0+am)*D_ + k0 + ak2];
        float4 q[16];
        #pragma unroll
        for (int i = 0; i < 8; i++) {
            q[2*i]   = *(const float4*)&W1[(size_t)(k0+bk8+i)*(2*D_) + bn8];
            q[2*i+1] = *(const float4*)&W1[(size_t)(k0+bk8+i)*(2*D_) + bn8 + 4];
        }
        if (ksi) __syncthreads();
        if (tid < 128) *(uint*)&As[apos] = av;
        #pragma unroll
        for (int jn = 0; jn < 8; jn++) {
            int n = bn8 + jn;
            float e0 = (jn<4)? ((const float*)&q[0])[jn]  : ((const float*)&q[1])[jn-4];
            float e1 = (jn<4)? ((const float*)&q[2])[jn]  : ((const float*)&q[3])[jn-4];
            float e2 = (jn<4)? ((const float*)&q[4])[jn]  : ((const float*)&q[5])[jn-4];
            float e3 = (jn<4)? ((const float*)&q[6])[jn]  : ((const float*)&q[7])[jn-4];
            float e4 = (jn<4)? ((const float*)&q[8])[jn]  : ((const float*)&q[9])[jn-4];
            float e5 = (jn<4)? ((const float*)&q[10])[jn] : ((const float*)&q[11])[jn-4];
            float e6 = (jn<4)? ((const float*)&q[12])[jn] : ((const float*)&q[13])[jn-4];
            float e7 = (jn<4)? ((const float*)&q[14])[jn] : ((const float*)&q[15])[jn-4];
            uint4 wv;
            wv.x = pack2_bf(e0, e1); wv.y = pack2_bf(e2, e3);
            wv.z = pack2_bf(e4, e5); wv.w = pack2_bf(e6, e7);
            *(uint4*)&Bs[n*40 + ((((bk8>>3) ^ (n&3))) << 3)] = wv;
        }
        __syncthreads();
        const ushort* ab = As + c15*40 + gx;
        #pragma unroll
        for (int nt = 0; nt < 8; nt++) {
            int n = w*128 + nt*16 + c15;
            bf16x8 af  = *(const bf16x8*)ab;
            bf16x8 bfr = *(const bf16x8*)&Bs[n*40 + gx];
            acc1[nt] = __builtin_amdgcn_mfma_f32_16x16x32_bf16(af, bfr, acc1[nt], 0, 0, 0);
        }
    }
    __syncthreads();

    if (g < 2) {
        #pragma unroll
        for (int nt = 0; nt < 8; nt++) {
            int c = w*128 + nt*16 + c15;
            float bias = b1[c];
            #pragma unroll
            for (int i = 0; i < 4; i++) {
                int r = g*4 + i;
                float v = acc1[nt][i] + bias;
                v = 0.5f * v * (1.0f + erff(v * 0.70710678118654752f));
                lnb[r*513 + c] = v;
            }
        }
    }
    __syncthreads();
    if (tid < 128) {
        int rr = tid >> 4, sl = tid & 15;
        float sum = 0.f, sq = 0.f;
        #pragma unroll
        for (int j = 0; j < 32; j++) {
            float v = lnb[rr*513 + sl + 16*j];
            sum += v; sq += v*v;
        }
        #pragma unroll
        for (int m = 1; m < 16; m <<= 1) { sum += __shfl_xor(sum, m); sq += __shfl_xor(sq, m); }
        if (sl == 0) {
            float mean = sum * (1.0f/(2*D_));
            float var  = fmaxf(sq * (1.0f/(2*D_)) - mean*mean, 0.f);
            stat[rr] = make_float2(mean, rsqrtf(var + 1e-12f));
        }
    }
    __syncthreads();
    if (tid < 128) {
        int rr = tid & 7, s2 = tid >> 3;
        float2 ms = stat[rr];
        int c0 = s2 * 32;
        #pragma unroll
        for (int q = 0; q < 8; q++) {
            int c = c0 + q*4;
            float4 v = *(const float4*)&lnb[rr*513 + c];
            float4 gm = *(const float4*)&gf[c];
            float4 bt = *(const float4*)&bfv[c];
            float h0 = (v.x - ms.x)*ms.y*gm.x + bt.x;
            float h1 = (v.y - ms.x)*ms.y*gm.y + bt.y;
            float h2 = (v.z - ms.x)*ms.y*gm.z + bt.z;
            float h3 = (v.w - ms.x)*ms.y*gm.w + bt.w;
            *(uint2*)&fout[(size_t)(m0+rr)*(2*D_) + c] = make_uint2(pack2_bf(h0,h1), pack2_bf(h2,h3));
        }
    }
}

// ---- gemm_f2: out = f@W2 + b2f + resid ----
__global__ __launch_bounds__(256, 4)
void gemm_f2(const ushort* __restrict__ fbuf, const float* __restrict__ W2,
             const float* __restrict__ b2f, const float* __restrict__ resid,
             float* __restrict__ outp)
{
    __shared__ __align__(16) ushort As[16*40];
    __shared__ __align__(16) ushort Bs[256*40];
    __shared__ float esc[8*257];

    int m0 = blockIdx.x * 8;
    int tid = threadIdx.x;
    int lane = tid & 63;
    int w = tid >> 6;
    int g = lane >> 4, c15 = lane & 15;
    int gx = (g ^ (c15 & 3)) * 8;

    int am  = tid >> 4;
    int ak2 = (tid & 15) * 2;
    int apos = am*40 + ((((ak2>>3) ^ (am&3))) << 3) + (ak2 & 7);
    int bn8 = (tid & 31) * 8;
    int bkq = (tid >> 5) * 4;
    int bposR = ((bkq >> 3) << 3) + (bkq & 7);

    f32x4 acc[4];
    #pragma unroll
    for (int j = 0; j < 4; j++) acc[j] = (f32x4){0.f,0.f,0.f,0.f};

    for (int ksi = 0; ksi < 16; ksi++) {
        int k0 = ksi * 32;
        uint av = 0;
        if (tid < 128) av = *(const uint*)&fbuf[(size_t)(m0+am)*(2*D_) + k0 + ak2];
        float4 lo[4], hi[4];
        #pragma unroll
        for (int i = 0; i < 4; i++) {
            lo[i] = *(const float4*)&W2[(size_t)(k0+bkq+i)*D_ + bn8];
            hi[i] = *(const float4*)&W2[(size_t)(k0+bkq+i)*D_ + bn8 + 4];
        }
        if (ksi) __syncthreads();
        if (tid < 128) *(uint*)&As[apos] = av;
        #pragma unroll
        for (int jn = 0; jn < 8; jn++) {
            int n = bn8 + jn;
            float v0 = (jn<4)? ((const float*)&lo[0])[jn] : ((const float*)&hi[0])[jn-4];
            float v1 = (jn<4)? ((const float*)&lo[1])[jn] : ((const float*)&hi[1])[jn-4];
            float v2 = (jn<4)? ((const float*)&lo[2])[jn] : ((const float*)&hi[2])[jn-4];
            float v3 = (jn<4)? ((const float*)&lo[3])[jn] : ((const float*)&hi[3])[jn-4];
            uint2 wv; wv.x = pack2_bf(v0, v1); wv.y = pack2_bf(v2, v3);
            *(uint2*)&Bs[n*40 + (bposR ^ ((n&3)<<3))] = wv;
        }
        __syncthreads();
        const ushort* ab = As + c15*40 + gx;
        #pragma unroll
        for (int nt = 0; nt < 4; nt++) {
            int n = w*64 + nt*16 + c15;
            bf16x8 af  = *(const bf16x8*)ab;
            bf16x8 bfr = *(const bf16x8*)&Bs[n*40 + gx];
            acc[nt] = __builtin_amdgcn_mfma_f32_16x16x32_bf16(af, bfr, acc[nt], 0, 0, 0);
        }
    }
    __syncthreads();

    if (g < 2) {
        #pragma unroll
        for (int nt = 0; nt < 4; nt++) {
            int c = w*64 + nt*16 + c15;
            #pragma unroll
            for (int i = 0; i < 4; i++)
                esc[(g*4+i)*257 + c] = acc[nt][i];
        }
    }
    __syncthreads();
    if (tid < 128) {
        int rr = tid & 7, s2 = tid >> 3;
        int c0 = s2 * 16;
        #pragma unroll
        for (int q = 0; q < 4; q++) {
            int c = c0 + q*4;
            float4 v  = *(const float4*)&esc[rr*257 + c];
            float4 bb = *(const float4*)&b2f[c];
            float4 rs = *(const float4*)&resid[(size_t)(m0+rr)*D_ + c];
            float4 o = make_float4(v.x+bb.x+rs.x, v.y+bb.y+rs.y, v.z+bb.z+rs.z, v.w+bb.w+rs.w);
            *(float4*)&outp[(size_t)(m0+rr)*D_ + c] = o;
        }
    }
}

extern "C" void kernel_launch(void* const* d_in, const int* in_sizes, int n_in,
                              void* d_out, int out_size, void* d_ws, size_t ws_size,
                              hipStream_t stream)
{
    const float* adj    = (const float*)d_in[0];
    const float* degree = (const float*)d_in[1];
    const float* x      = (const float*)d_in[2];
    const float* kern   = (const float*)d_in[3];
    const float* Wv     = (const float*)d_in[4];
    const float* Bv     = (const float*)d_in[5];
    const float* W0     = (const float*)d_in[6];
    const float* gamma2 = (const float*)d_in[7];
    const float* beta2  = (const float*)d_in[8];
    const float* W1     = (const float*)d_in[9];
    const float* b1     = (const float*)d_in[10];
    const float* gf     = (const float*)d_in[11];
    const float* bf_    = (const float*)d_in[12];
    const float* W2     = (const float*)d_in[13];
    const float* b2f    = (const float*)d_in[14];
    float* out = (float*)d_out;
    float* ws  = (float*)d_ws;

    size_t off = 0;
    float* T0    = ws + off; off += (size_t)ROWS_*D_/2;     // bf16 panels (1MB)
    float* T1    = ws + off; off += (size_t)ROWS_*D_/2;
    float* resid = ws + off; off += (size_t)ROWS_*D_;       // fp32
    float* hbufF = ws + off; off += (size_t)ROWS_*D_/2;     // bf16
    float* foutF = ws + off; off += (size_t)ROWS_*D_;       // bf16 (2D cols)
    float* PpF   = ws + off; off += (size_t)KS_*ROWS_*D_/2; // bf16 slabs (8MB)
    ushort* adjp = (ushort*)(ws + off);                      // 37.75MB bf16

    ushort* T0b = (ushort*)T0;
    ushort* T1b = (ushort*)T1;
    ushort* hb  = (ushort*)hbufF;
    ushort* fb  = (ushort*)foutF;
    ushort* Pp  = (ushort*)PpF;

    gemm_v<<<ROWS_/8, 256, 0, stream>>>(x, Wv, Bv, T0b);

    int chain_grid  = B_*64*KS_;     // 1024
    int reduce_grid = SLABU2_/256;   // 512
    chain_mfma<1><<<chain_grid, 256, 0, stream>>>(adj, adjp, kern, T0b, Pp, 3);
    chain_reduce<<<reduce_grid, 256, 0, stream>>>(Pp, T1b);
    chain_mfma<0><<<chain_grid, 256, 0, stream>>>(adj, adjp, kern, T1b, Pp, 2);
    chain_reduce<<<reduce_grid, 256, 0, stream>>>(Pp, T0b);
    chain_mfma<0><<<chain_grid, 256, 0, stream>>>(adj, adjp, kern, T0b, Pp, 1);
    chain_reduce<<<reduce_grid, 256, 0, stream>>>(Pp, T1b);
    chain_mfma<0><<<chain_grid, 256, 0, stream>>>(adj, adjp, kern, T1b, Pp, 0);

    gemm_r <<<ROWS_/8, 256, 0, stream>>>(Pp, degree, W0, x, gamma2, beta2, resid, hb);
    gemm_f1<<<ROWS_/8, 256, 0, stream>>>(hb, W1, b1, gf, bf_, fb);
    gemm_f2<<<ROWS_/8, 256, 0, stream>>>(fb, W2, b2f, resid, out);
}